// Round 2
// baseline (239.535 us; speedup 1.0000x reference)
//
#include <hip/hip_runtime.h>
#include <hip/hip_bf16.h>
#include <math.h>

#define INV_T (1.0f / 0.07f)

typedef __bf16 bf16x8 __attribute__((ext_vector_type(8)));
typedef float f32x4 __attribute__((ext_vector_type(4)));

__device__ __forceinline__ void gld16(const void* g, void* l) {
    __builtin_amdgcn_global_load_lds(
        (const __attribute__((address_space(1))) unsigned int*)g,
        (__attribute__((address_space(3))) unsigned int*)l,
        16, 0, 0);
}

// ---------------- normalize + bf16 pack + positive dot + S-zero ------------
__global__ __launch_bounds__(256) void norm_kernel(
    const float4* __restrict__ f1, const float4* __restrict__ f2,
    ushort4* __restrict__ F, float* __restrict__ S, float* __restrict__ P,
    int* __restrict__ cnt, int B) {
    const int i = blockIdx.x;
    const int t = threadIdx.x;

    float4 x = f1[i * 256 + t];
    float4 y = f2[i * 256 + t];

    float s1 = x.x * x.x + x.y * x.y + x.z * x.z + x.w * x.w;
    float s2 = y.x * y.x + y.y * y.y + y.z * y.z + y.w * y.w;
    float dd = x.x * y.x + x.y * y.y + x.z * y.z + x.w * y.w;

    for (int o = 32; o > 0; o >>= 1) {
        s1 += __shfl_down(s1, o);
        s2 += __shfl_down(s2, o);
        dd += __shfl_down(dd, o);
    }
    __shared__ float red[4][3];
    const int wv = t >> 6, ln = t & 63;
    if (ln == 0) { red[wv][0] = s1; red[wv][1] = s2; red[wv][2] = dd; }
    __syncthreads();
    s1 = red[0][0] + red[1][0] + red[2][0] + red[3][0];
    s2 = red[0][1] + red[1][1] + red[2][1] + red[3][1];
    dd = red[0][2] + red[1][2] + red[2][2] + red[3][2];

    const float rn1 = 1.0f / fmaxf(sqrtf(s1), 1e-12f);
    const float rn2 = 1.0f / fmaxf(sqrtf(s2), 1e-12f);

    union { ushort4 u; __hip_bfloat16 h[4]; } p;
    p.h[0] = __float2bfloat16(x.x * rn1);
    p.h[1] = __float2bfloat16(x.y * rn1);
    p.h[2] = __float2bfloat16(x.z * rn1);
    p.h[3] = __float2bfloat16(x.w * rn1);
    F[(size_t)i * 256 + t] = p.u;
    p.h[0] = __float2bfloat16(y.x * rn2);
    p.h[1] = __float2bfloat16(y.y * rn2);
    p.h[2] = __float2bfloat16(y.z * rn2);
    p.h[3] = __float2bfloat16(y.w * rn2);
    F[(size_t)(B + i) * 256 + t] = p.u;

    if (t == 0) {
        P[i] = dd * rn1 * rn2;
        S[i] = 0.0f;
        S[B + i] = 0.0f;
        if (i == 0) *cnt = 0;
    }
}

// ---------------- fused sim-GEMM, 256x256 tile, 8-phase counted-vmcnt ------
// Off-diagonal tiles (ti<tj, 496) dispatched first with XCD-chunked order;
// diagonal tiles (32) last (short: below-diag quad clusters skipped) to fill
// the scheduling tail. Last-finishing block runs the finalize reduction.

#define BARRIER() asm volatile("s_barrier" ::: "memory")
#define VMCNT6()  asm volatile("s_waitcnt vmcnt(6)" ::: "memory")
#define VMCNT0()  asm volatile("s_waitcnt vmcnt(0)" ::: "memory")

// ks-outer: dependency distance 8 between MFMAs sharing an accumulator
#define QUAD_MFMA(MH, NH)                                                     \
    _Pragma("unroll") for (int ks = 0; ks < 2; ++ks)                          \
    _Pragma("unroll") for (int mi = 0; mi < 4; ++mi)                          \
    _Pragma("unroll") for (int ni = 0; ni < 2; ++ni)                          \
        acc[(MH) * 4 + mi][(NH) * 2 + ni] =                                   \
            __builtin_amdgcn_mfma_f32_16x16x32_bf16(                          \
                af[mi][ks], bf[NH][ni][ks],                                   \
                acc[(MH) * 4 + mi][(NH) * 2 + ni], 0, 0, 0);

#define PH_COMPUTE(MH, NH, SK)                                                \
    BARRIER();                                                                \
    asm volatile("s_waitcnt lgkmcnt(0)" ::: "memory");                        \
    __builtin_amdgcn_sched_barrier(0);                                        \
    if (!(SK)) {                                                              \
        __builtin_amdgcn_s_setprio(1);                                        \
        QUAD_MFMA(MH, NH);                                                    \
        __builtin_amdgcn_s_setprio(0);                                        \
    }                                                                         \
    __builtin_amdgcn_sched_barrier(0);

__global__ __launch_bounds__(512, 2) void sim_kernel(
    const ushort* __restrict__ F, float* __restrict__ S,
    const float* __restrict__ P, float* __restrict__ out,
    int* __restrict__ cnt, int Nn, int Bn, int noff, int chunk) {
    // [buf][A=0/B=1][half][128 rows x 64 cols] bf16 = 128 KB
    __shared__ __align__(16) ushort lds[2][2][2][128 * 64];

    // ---- tile decode ----
    const int p = blockIdx.x;
    int ti, tj;
    if (p < noff) {
        const int o = chunk ? (p & 7) * chunk + (p >> 3) : p;
        // strict-upper enum: o = tj*(tj-1)/2 + ti, ti < tj
        int t = (int)((1.0f + sqrtf(8.0f * (float)o + 1.0f)) * 0.5f);
        while (t * (t - 1) / 2 > o) --t;
        while ((t + 1) * t / 2 <= o) ++t;
        tj = t;
        ti = o - t * (t - 1) / 2;
    } else {
        ti = tj = p - noff;
    }
    const int bRow = ti * 256, bCol = tj * 256;

    const int tid = threadIdx.x;
    const int wave = tid >> 6, lane = tid & 63;
    const int wr = wave >> 2, wc = wave & 3;      // 2 x 4 wave grid
    const int quad = lane >> 4, l16 = lane & 15;
    const int swz = l16 & 7;

    // below-diagonal quad-cluster skip masks (wave-uniform; false off-diag)
    const int rB = bRow + wr * 128, cB = bCol + wc * 64;
    const bool sk00 = rB > cB + 31;
    const bool sk01 = rB > cB + 63;
    const bool sk10 = rB + 64 > cB + 31;
    const bool sk11 = rB + 64 > cB + 63;

    // staging: thread stages chunks tid and tid+512 of a 128x64 half-tile
    const int r0 = tid >> 3;                          // 0..63
    const int scol = ((tid & 7) ^ (r0 & 7)) * 8;      // pre-swizzled src chunk
    const size_t gA = (size_t)(bRow + r0) * 1024 + scol;
    const size_t gB = (size_t)(bCol + r0) * 1024 + scol;

    auto stage = [&](int bsel, int ab, int h, int kb) {
        const ushort* g = F + (ab ? gB : gA) + (size_t)h * (128 * 1024) + kb;
        ushort* l = &lds[bsel][ab][h][tid * 8];
        gld16(g, l);                       // rows r0
        gld16(g + 64 * 1024, l + 512 * 8); // rows r0+64
    };

    bf16x8 af[4][2];      // A frags of current m-half
    bf16x8 bf[2][2][2];   // all B frags of current K-tile [nh][ni][ks]
    f32x4 acc[8][4];
#pragma unroll
    for (int a = 0; a < 8; ++a)
#pragma unroll
        for (int b = 0; b < 4; ++b) acc[a][b] = (f32x4){0.0f, 0.0f, 0.0f, 0.0f};

    auto loadA = [&](int bsel, int mh) {
#pragma unroll
        for (int mi = 0; mi < 4; ++mi)
#pragma unroll
            for (int ks = 0; ks < 2; ++ks)
                af[mi][ks] = *(const bf16x8*)&lds[bsel][0][wr]
                    [(mh * 64 + mi * 16 + l16) * 64 + ((ks * 4 + quad) ^ swz) * 8];
    };
    auto loadB = [&](int bsel, int nh) {
#pragma unroll
        for (int ni = 0; ni < 2; ++ni)
#pragma unroll
            for (int ks = 0; ks < 2; ++ks)
                bf[nh][ni][ks] = *(const bf16x8*)&lds[bsel][1][wc >> 1]
                    [((wc & 1) * 64 + nh * 32 + ni * 16 + l16) * 64 +
                     ((ks * 4 + quad) ^ swz) * 8];
    };

    // ---- prologue: tile0 full into buf0; tile1 {B0,B1,A0} into buf1 ----
    stage(0, 0, 0, 0); stage(0, 0, 1, 0); stage(0, 1, 0, 0); stage(0, 1, 1, 0);
    stage(1, 1, 0, 64); stage(1, 1, 1, 64); stage(1, 0, 0, 64);
    VMCNT6();   // tile0 landed; tile1's 3 stages may stay in flight
    BARRIER();

#pragma unroll 1
    for (int it = 0; it < 7; ++it) {
        const int kb0 = it * 128;  // K offset of tile t0 = 2*it
        // ---------- K-tile t0 (buf0) ----------
        // ph1 (0,0): read A-mh0 + B-nh0; stage buf1.A1 <- t1
        loadA(0, 0); loadB(0, 0);
        stage(1, 0, 1, kb0 + 64);
        PH_COMPUTE(0, 0, sk00);
        BARRIER();
        // ph2 (0,1): read B-nh1; stage buf0.B0 <- t0+2
        loadB(0, 1);
        stage(0, 1, 0, kb0 + 128);
        PH_COMPUTE(0, 1, sk01);
        BARRIER();
        // ph3 (1,0): read A-mh1; stage buf0.B1 <- t0+2
        loadA(0, 1);
        stage(0, 1, 1, kb0 + 128);
        PH_COMPUTE(1, 0, sk10);
        BARRIER();
        // ph4 (1,1): stage buf0.A0 <- t0+2; counted vmcnt
        stage(0, 0, 0, kb0 + 128);
        PH_COMPUTE(1, 1, sk11);
        VMCNT6();   // drains buf1 stages {prev ph6,7,8, ph1} for ph5 reads
        BARRIER();
        // ---------- K-tile t1 (buf1) ----------
        // ph5 (0,0): read A-mh0 + B-nh0; stage buf0.A1 <- t0+2
        loadA(1, 0); loadB(1, 0);
        stage(0, 0, 1, kb0 + 128);
        PH_COMPUTE(0, 0, sk00);
        BARRIER();
        // ph6 (0,1): read B-nh1; stage buf1.B0 <- t1+2
        loadB(1, 1);
        stage(1, 1, 0, kb0 + 192);
        PH_COMPUTE(0, 1, sk01);
        BARRIER();
        // ph7 (1,0): read A-mh1; stage buf1.B1 <- t1+2
        loadA(1, 1);
        stage(1, 1, 1, kb0 + 192);
        PH_COMPUTE(1, 0, sk10);
        BARRIER();
        // ph8 (1,1): stage buf1.A0 <- t1+2; counted vmcnt
        stage(1, 0, 0, kb0 + 192);
        PH_COMPUTE(1, 1, sk11);
        VMCNT6();   // drains buf0 stages {ph2..ph5} for next-iter ph1 reads
        BARRIER();
    }

    // ---- K-tile 14 (buf0); only remaining stage = buf1.A1 <- tile15 ----
    loadA(0, 0); loadB(0, 0);
    stage(1, 0, 1, 960);
    if (!sk00) { QUAD_MFMA(0, 0); }
    loadB(0, 1);
    if (!sk01) { QUAD_MFMA(0, 1); }
    loadA(0, 1);
    if (!sk10) { QUAD_MFMA(1, 0); }
    if (!sk11) { QUAD_MFMA(1, 1); }
    VMCNT0();
    BARRIER();
    // ---- K-tile 15 (buf1); no stages, compiler-managed waits suffice ----
    loadA(1, 0); loadB(1, 0);
    if (!sk00) { QUAD_MFMA(0, 0); }
    loadB(1, 1);
    if (!sk01) { QUAD_MFMA(0, 1); }
    loadA(1, 1);
    if (!sk10) { QUAD_MFMA(1, 0); }
    if (!sk11) { QUAD_MFMA(1, 1); }

    // ---- epilogue: e = (gRow<gCol) ? exp((c-1)/T) : 0; row+col sums ----
#pragma unroll
    for (int a = 0; a < 8; ++a)
#pragma unroll
        for (int b = 0; b < 4; ++b)
#pragma unroll
            for (int r = 0; r < 4; ++r) {
                const int gRow = bRow + wr * 128 + (a >> 2) * 64 + (a & 3) * 16 + quad * 4 + r;
                const int gCol = bCol + wc * 64 + (b >> 1) * 32 + (b & 1) * 16 + l16;
                acc[a][b][r] = (gRow < gCol)
                    ? __expf((acc[a][b][r] - 1.0f) * INV_T) : 0.0f;
            }

    // row sums: reduce over l16, atomic per (a, r, quad)
#pragma unroll
    for (int a = 0; a < 8; ++a)
#pragma unroll
        for (int r = 0; r < 4; ++r) {
            const int gRow = bRow + wr * 128 + (a >> 2) * 64 + (a & 3) * 16 + quad * 4 + r;
            float v = acc[a][0][r] + acc[a][1][r] + acc[a][2][r] + acc[a][3][r];
            v += __shfl_xor(v, 1);
            v += __shfl_xor(v, 2);
            v += __shfl_xor(v, 4);
            v += __shfl_xor(v, 8);
            if (l16 == 0) atomicAdd(&S[gRow], v);
        }

    // col sums: reduce over quad, atomic per (b, l16)
#pragma unroll
    for (int b = 0; b < 4; ++b) {
        float cv = 0.0f;
#pragma unroll
        for (int a = 0; a < 8; ++a)
#pragma unroll
            for (int r = 0; r < 4; ++r) cv += acc[a][b][r];
        cv += __shfl_xor(cv, 16);
        cv += __shfl_xor(cv, 32);
        if (quad == 0) {
            const int gCol = bCol + wc * 64 + (b >> 1) * 32 + (b & 1) * 16 + l16;
            atomicAdd(&S[gCol], cv);
        }
    }

    // ---- last-block-done finalize (saves one kernel launch) ----
    __threadfence();
    __shared__ int lastFlag;
    if (tid == 0) lastFlag = (atomicAdd(cnt, 1) == (int)gridDim.x - 1);
    __syncthreads();
    if (!lastFlag) return;

    // S read through atomics (coherent point); P safe via kernel-boundary acq
    float s = 0.0f;
    for (int i = tid; i < Nn; i += 512) s += __logf(atomicAdd(&S[i], 0.0f));
    float pp = 0.0f;
    for (int i = tid; i < Bn; i += 512) pp += P[i];
    for (int o = 32; o > 0; o >>= 1) {
        s += __shfl_down(s, o);
        pp += __shfl_down(pp, o);
    }
    __shared__ float red[8][2];
    if (lane == 0) { red[wave][0] = s; red[wave][1] = pp; }
    __syncthreads();
    if (tid == 0) {
        float sl = 0.0f, ps = 0.0f;
#pragma unroll
        for (int w = 0; w < 8; ++w) { sl += red[w][0]; ps += red[w][1]; }
        out[0] = INV_T + sl / (float)Nn - ps * (2.0f * INV_T / (float)Nn);
    }
}

extern "C" void kernel_launch(void* const* d_in, const int* in_sizes, int n_in,
                              void* d_out, int out_size, void* d_ws, size_t ws_size,
                              hipStream_t stream) {
    const int D = 1024;
    const int B = in_sizes[0] / D;       // 4096
    const int N = 2 * B;                 // 8192
    const int M = N / 256;               // 32 tile rows/cols
    const int noff = M * (M - 1) / 2;    // 496 off-diagonal tiles
    const int ntiles = noff + M;         // 528
    const int chunk = (noff % 8 == 0) ? noff / 8 : 0;  // XCD chunking

    const float* f1 = (const float*)d_in[0];
    const float* f2 = (const float*)d_in[1];

    __hip_bfloat16* F = (__hip_bfloat16*)d_ws;  // N*D bf16 = 16 MB
    float* S = (float*)((char*)d_ws + (size_t)N * D * sizeof(__hip_bfloat16));
    float* P = S + N;                    // B floats
    int* cnt = (int*)(P + B);

    norm_kernel<<<dim3(B), dim3(256), 0, stream>>>(
        (const float4*)f1, (const float4*)f2, (ushort4*)F, S, P, cnt, B);
    sim_kernel<<<dim3(ntiles), dim3(512), 0, stream>>>(
        (const ushort*)F, S, P, (float*)d_out, cnt, N, B, noff, chunk);
}

// Round 3
// 181.219 us; speedup vs baseline: 1.3218x; 1.3218x over previous
//
#include <hip/hip_runtime.h>
#include <hip/hip_bf16.h>
#include <math.h>

#define INV_T (1.0f / 0.07f)

typedef __bf16 bf16x8 __attribute__((ext_vector_type(8)));
typedef float f32x4 __attribute__((ext_vector_type(4)));

__device__ __forceinline__ void gld16(const void* g, void* l) {
    __builtin_amdgcn_global_load_lds(
        (const __attribute__((address_space(1))) unsigned int*)g,
        (__attribute__((address_space(3))) unsigned int*)l,
        16, 0, 0);
}

// ---------------- normalize + bf16 pack + positive dot + S-zero ------------
// one block per pair-row i; also zeroes S[i], S[B+i]; P[i] = cos(f1_i,f2_i)
__global__ __launch_bounds__(256) void norm_kernel(
    const float4* __restrict__ f1, const float4* __restrict__ f2,
    ushort4* __restrict__ F, float* __restrict__ S, float* __restrict__ P,
    int* __restrict__ cnt, int B) {
    const int i = blockIdx.x;
    const int t = threadIdx.x;

    float4 x = f1[i * 256 + t];
    float4 y = f2[i * 256 + t];

    float s1 = x.x * x.x + x.y * x.y + x.z * x.z + x.w * x.w;
    float s2 = y.x * y.x + y.y * y.y + y.z * y.z + y.w * y.w;
    float dd = x.x * y.x + x.y * y.y + x.z * y.z + x.w * y.w;

    for (int o = 32; o > 0; o >>= 1) {
        s1 += __shfl_down(s1, o);
        s2 += __shfl_down(s2, o);
        dd += __shfl_down(dd, o);
    }
    __shared__ float red[4][3];
    const int wv = t >> 6, ln = t & 63;
    if (ln == 0) { red[wv][0] = s1; red[wv][1] = s2; red[wv][2] = dd; }
    __syncthreads();
    s1 = red[0][0] + red[1][0] + red[2][0] + red[3][0];
    s2 = red[0][1] + red[1][1] + red[2][1] + red[3][1];
    dd = red[0][2] + red[1][2] + red[2][2] + red[3][2];

    const float rn1 = 1.0f / fmaxf(sqrtf(s1), 1e-12f);
    const float rn2 = 1.0f / fmaxf(sqrtf(s2), 1e-12f);

    union { ushort4 u; __hip_bfloat16 h[4]; } p;
    p.h[0] = __float2bfloat16(x.x * rn1);
    p.h[1] = __float2bfloat16(x.y * rn1);
    p.h[2] = __float2bfloat16(x.z * rn1);
    p.h[3] = __float2bfloat16(x.w * rn1);
    F[(size_t)i * 256 + t] = p.u;
    p.h[0] = __float2bfloat16(y.x * rn2);
    p.h[1] = __float2bfloat16(y.y * rn2);
    p.h[2] = __float2bfloat16(y.z * rn2);
    p.h[3] = __float2bfloat16(y.w * rn2);
    F[(size_t)(B + i) * 256 + t] = p.u;

    if (t == 0) {
        P[i] = dd * rn1 * rn2;
        S[i] = 0.0f;
        S[B + i] = 0.0f;
        if (i == 0) *cnt = 0;
    }
}

// ---------------- fused sim-GEMM + exp + row/col-sum (upper triangle) ------
// 128x256 block tile (rows ti*128, cols tj*256), tiles with ti <= 2*tj+1.
// Rule: count ONLY strictly-upper elements (gRow < gCol); credit exp to both
// S[gRow] and S[gCol]. Each unordered pair is computed exactly once; diagonal
// excluded automatically. 4 waves in 2x2, each wave 64x128 (4x8 of 16x16x32).
// XOR-swizzled LDS: chunk slot s at row r holds global chunk s^(r&7).
// Last-finishing block runs the finalize reduction (atomic-coherent reads,
// NO agent fence: a vmcnt drain orders our S-atomics before the cnt bump).
__global__ __launch_bounds__(256, 2) void sim_kernel(
    const __hip_bfloat16* __restrict__ F, float* __restrict__ S,
    const float* __restrict__ P, float* __restrict__ out,
    int* __restrict__ cnt, int N, int B, int D) {
    __shared__ __align__(16) __hip_bfloat16 As[128][64];  // 16 KB
    __shared__ __align__(16) __hip_bfloat16 Bs[256][64];  // 32 KB

    // ---- decode linear block id -> (ti, tj): k = tj^2 + tj + ti ----
    const int k = blockIdx.x;
    int tj = (int)((sqrtf(4.0f * (float)k + 1.0f) - 1.0f) * 0.5f);
    while ((tj + 1) * (tj + 2) <= k) ++tj;
    while (tj * (tj + 1) > k) --tj;
    const int ti = k - tj * (tj + 1);  // in [0, 2*tj+2)
    const int bRow = ti * 128;
    const int bCol = tj * 256;

    const int tid  = threadIdx.x;
    const int wave = tid >> 6;
    const int lane = tid & 63;
    const int quad = lane >> 4;
    const int l16  = lane & 15;

    const int srow   = lane >> 3;                 // 0..7
    const int ldsOff = (lane & 7) * 8;            // dest slot (elements)
    const int srcOff = ((lane & 7) ^ srow) * 8;   // swizzled global chunk

    const int waveRow = (wave >> 1) * 64;
    const int waveCol = (wave & 1) * 128;
    const int swz = l16 & 7;

    f32x4 acc[4][8];
#pragma unroll
    for (int mi = 0; mi < 4; ++mi)
#pragma unroll
        for (int ni = 0; ni < 8; ++ni)
            acc[mi][ni] = (f32x4){0.0f, 0.0f, 0.0f, 0.0f};

    for (int kb = 0; kb < D; kb += 64) {
#pragma unroll
        for (int p = 0; p < 4; ++p) {
            const int rowT = (p * 4 + wave) * 8 + srow;   // 0..127
            gld16(&F[(size_t)(bRow + rowT) * D + kb + srcOff], &As[rowT][ldsOff]);
        }
#pragma unroll
        for (int p = 0; p < 8; ++p) {
            const int rowT = (p * 4 + wave) * 8 + srow;   // 0..255 (p*4+wave spans 0..31)
            gld16(&F[(size_t)(bCol + rowT) * D + kb + srcOff], &Bs[rowT][ldsOff]);
        }
        __syncthreads();

#pragma unroll
        for (int ks = 0; ks < 2; ++ks) {
            const int slot = ((ks * 4 + quad) ^ swz) * 8;
            bf16x8 bf[8];
#pragma unroll
            for (int ni = 0; ni < 8; ++ni)
                bf[ni] = *(const bf16x8*)&Bs[waveCol + ni * 16 + l16][slot];
#pragma unroll
            for (int mi = 0; mi < 4; ++mi) {
                const bf16x8 af = *(const bf16x8*)&As[waveRow + mi * 16 + l16][slot];
#pragma unroll
                for (int ni = 0; ni < 8; ++ni)
                    acc[mi][ni] = __builtin_amdgcn_mfma_f32_16x16x32_bf16(
                        af, bf[ni], acc[mi][ni], 0, 0, 0);
            }
        }
        __syncthreads();
    }

    // ---- epilogue: e = (gRow<gCol) ? exp((c-1)/T) : 0; row+col sums ----
#pragma unroll
    for (int mi = 0; mi < 4; ++mi)
#pragma unroll
        for (int ni = 0; ni < 8; ++ni)
#pragma unroll
            for (int r = 0; r < 4; ++r) {
                const int gRow = bRow + waveRow + mi * 16 + quad * 4 + r;
                const int gCol = bCol + waveCol + ni * 16 + l16;
                acc[mi][ni][r] = (gRow < gCol)
                    ? __expf((acc[mi][ni][r] - 1.0f) * INV_T) : 0.0f;
            }

    // row sums
#pragma unroll
    for (int mi = 0; mi < 4; ++mi)
#pragma unroll
        for (int r = 0; r < 4; ++r) {
            const int gRow = bRow + waveRow + mi * 16 + quad * 4 + r;
            float v = 0.0f;
#pragma unroll
            for (int ni = 0; ni < 8; ++ni) v += acc[mi][ni][r];
            v += __shfl_xor(v, 1);
            v += __shfl_xor(v, 2);
            v += __shfl_xor(v, 4);
            v += __shfl_xor(v, 8);
            if (l16 == 0) atomicAdd(&S[gRow], v);
        }

    // col sums (transpose contribution)
#pragma unroll
    for (int ni = 0; ni < 8; ++ni) {
        float cv = 0.0f;
#pragma unroll
        for (int mi = 0; mi < 4; ++mi)
#pragma unroll
            for (int r = 0; r < 4; ++r) cv += acc[mi][ni][r];
        cv += __shfl_xor(cv, 16);
        cv += __shfl_xor(cv, 32);
        if (quad == 0) atomicAdd(&S[bCol + waveCol + ni * 16 + l16], cv);
    }

    // ---- last-block-done finalize (saves one kernel launch) ----
    // Drain OUR outstanding S-atomics (vmcnt) before signalling; all S/cnt
    // traffic is device-scope atomics at the coherent point, so no agent
    // fence (and no L2 writeback/invalidate!) is needed.
    asm volatile("s_waitcnt vmcnt(0) lgkmcnt(0)" ::: "memory");
    __shared__ int lastFlag;
    if (tid == 0) lastFlag = (atomicAdd(cnt, 1) == (int)gridDim.x - 1);
    __syncthreads();
    if (!lastFlag) return;

    // S read through atomics (same coherent point as the RMWs above);
    // P was written by norm_kernel (prior launch) -> safe via plain loads.
    float s = 0.0f;
    for (int i = tid; i < N; i += 256) s += __logf(atomicAdd(&S[i], 0.0f));
    float pp = 0.0f;
    for (int i = tid; i < B; i += 256) pp += P[i];
    for (int o = 32; o > 0; o >>= 1) {
        s += __shfl_down(s, o);
        pp += __shfl_down(pp, o);
    }
    __shared__ float redf[4][2];
    if (lane == 0) { redf[wave][0] = s; redf[wave][1] = pp; }
    __syncthreads();
    if (tid == 0) {
        const float sl = redf[0][0] + redf[1][0] + redf[2][0] + redf[3][0];
        const float ps = redf[0][1] + redf[1][1] + redf[2][1] + redf[3][1];
        out[0] = INV_T + sl / (float)N - ps * (2.0f * INV_T / (float)N);
    }
}

extern "C" void kernel_launch(void* const* d_in, const int* in_sizes, int n_in,
                              void* d_out, int out_size, void* d_ws, size_t ws_size,
                              hipStream_t stream) {
    const int D = 1024;
    const int B = in_sizes[0] / D;   // 4096
    const int N = 2 * B;             // 8192
    const int M2 = N / 256;          // 32 col-tiles
    const int ntiles = M2 * M2 + M2; // sum over tj of (2*tj+2) = 1056

    const float* f1 = (const float*)d_in[0];
    const float* f2 = (const float*)d_in[1];

    __hip_bfloat16* F = (__hip_bfloat16*)d_ws;  // N*D bf16 = 16 MB
    float* S = (float*)((char*)d_ws + (size_t)N * D * sizeof(__hip_bfloat16));
    float* P = S + N;                // B floats
    int* cnt = (int*)(P + B);

    norm_kernel<<<dim3(B), dim3(256), 0, stream>>>(
        (const float4*)f1, (const float4*)f2, (ushort4*)F, S, P, cnt, B);
    sim_kernel<<<dim3(ntiles), dim3(256), 0, stream>>>(
        F, S, P, (float*)d_out, cnt, N, B, D);
}